// Round 7
// baseline (258.047 us; speedup 1.0000x reference)
//
#include <hip/hip_runtime.h>
#include <cstddef>

#define EPS 1e-5f
static constexpr int Bn = 64, Cn = 64, Hn = 56, Wn = 56, HWn = Hn * Wn; // 3136
static constexpr int RB = 7;          // output rows per band in k23
static constexpr int NBAND = 8;       // 56/7 -> 512 blocks = 2 resident per CU, zero tail
static constexpr int SLAB = 1808;     // cat slab: 224*8+16 ushorts (904 dw % 32 == 8 -> quad bank offs {0,8,16,24})

typedef __attribute__((ext_vector_type(8))) short short8;
typedef __attribute__((ext_vector_type(4))) unsigned short ushort4v;
typedef __attribute__((ext_vector_type(4))) float floatx4;
typedef __attribute__((ext_vector_type(16))) float floatx16;
typedef __attribute__((ext_vector_type(4))) unsigned int uintx4;
typedef __attribute__((ext_vector_type(2))) unsigned int uintx2;

__device__ __forceinline__ unsigned pack_rne(float a, float b) {
    unsigned ua = __float_as_uint(a), ub = __float_as_uint(b);
    ua = ua + 0x7fffu + ((ua >> 16) & 1u);
    ub = ub + 0x7fffu + ((ub >> 16) & 1u);
    return __builtin_amdgcn_perm(ub, ua, 0x07060302);
}
__device__ __forceinline__ unsigned pack_trunc(float a, float b) {
    return __builtin_amdgcn_perm(__float_as_uint(b), __float_as_uint(a), 0x07060302);
}
__device__ __forceinline__ uintx2 pmax2(uintx2 a, uintx2 b) {
    ushort4v r = __builtin_elementwise_max(*(ushort4v*)&a, *(ushort4v*)&b);
    return *(uintx2*)&r;
}
__device__ __forceinline__ float bf_lo(unsigned u) { return __uint_as_float(u << 16); }
__device__ __forceinline__ float bf_hi(unsigned u) { return __uint_as_float(u & 0xffff0000u); }

// Layouts (bf16):
//   node0: [b][chunk=8][px=3136][j=8]
//   cat (LDS, per 4-row pass): 16 slabs of SLAB ushorts; slab = chunk*2 + plane
//     (plane 0 = avg, 1 = maxsum), element [px_local<=224][j=8]

// ---------------------------------------------------------------------------
// K1: node0 = relu(bn1(conv1x1(x,w1))), 32x32x16 MFMA, direct global B loads,
// all 64 loads issued up front. XCD swizzle: XCD x computes images 8x..8x+7
// (matches k23's read set -> node0 write+read stays in the local 4MB L2).
// launch_bounds(256,3): 3 blocks/CU resident -> no residency tail.
// Numerics identical to rounds 4-6 (passed).
// ---------------------------------------------------------------------------
__global__ __launch_bounds__(256, 3) void k1_conv1(
    const float* __restrict__ x, const float* __restrict__ w1,
    const float* __restrict__ bg, const float* __restrict__ bb,
    const float* __restrict__ bm, const float* __restrict__ bv,
    unsigned short* __restrict__ node0)
{
    __shared__ float scs[64], shs[64];
    const int tid = threadIdx.x;
    if (tid < 64) {
        float sc = bg[tid] * rsqrtf(bv[tid] + EPS);
        scs[tid] = sc;
        shs[tid] = bb[tid] - bm[tid] * sc;
    }
    __syncthreads();
    const int lane = tid & 63;
    const int wv   = tid >> 6;
    const int n    = lane & 31;
    const int h    = lane >> 5;

    // A-frags: w1[oc = oct*32+n][kt*16 + h*8 + 0..7] * sc[oc]
    short8 afr0[4], afr1[4];
    {
        const float s0 = scs[n], s1 = scs[32 + n];
        #pragma unroll
        for (int kt = 0; kt < 4; ++kt) {
            const float* wp0 = w1 + (size_t)n * 64 + kt * 16 + h * 8;
            floatx4 f0 = *(const floatx4*)wp0;
            floatx4 f1 = *(const floatx4*)(wp0 + 4);
            uintx4 u;
            u.x = pack_rne(f0[0] * s0, f0[1] * s0);
            u.y = pack_rne(f0[2] * s0, f0[3] * s0);
            u.z = pack_rne(f1[0] * s0, f1[1] * s0);
            u.w = pack_rne(f1[2] * s0, f1[3] * s0);
            afr0[kt] = *(short8*)&u;
            const float* wp1 = wp0 + 32 * 64;
            floatx4 g0 = *(const floatx4*)wp1;
            floatx4 g1 = *(const floatx4*)(wp1 + 4);
            uintx4 v;
            v.x = pack_rne(g0[0] * s1, g0[1] * s1);
            v.y = pack_rne(g0[2] * s1, g0[3] * s1);
            v.z = pack_rne(g1[0] * s1, g1[1] * s1);
            v.w = pack_rne(g1[2] * s1, g1[3] * s1);
            afr1[kt] = *(short8*)&v;
        }
    }

    // XCD-matched block swizzle: bid -> (xcd, idx), XCD x covers px slice of
    // images 8x..8x+7 exactly (98*256 px = 8 images).
    const int bid = blockIdx.x;
    const int xcd = bid & 7;
    const int idx = bid >> 3;                     // 0..97
    const int P = (xcd * 98 + idx) * 256 + wv * 64;
    const int b = P / HWn, p0 = P - b * HWn;      // 64 | 3136: no image crossing
    const float* xb = x + (size_t)b * 64 * HWn + p0 + n;

    // issue ALL 64 B-operand loads up front (16 KB/wave in flight)
    float f0[4][8], f1[4][8];
    #pragma unroll
    for (int kt = 0; kt < 4; ++kt)
        #pragma unroll
        for (int j = 0; j < 8; ++j) {
            const float* xp = xb + (size_t)(kt * 16 + h * 8 + j) * HWn;
            f0[kt][j] = xp[0];
            f1[kt][j] = xp[32];
        }

    #pragma unroll
    for (int s = 0; s < 2; ++s) {
        floatx16 acc0, acc1;
        #pragma unroll
        for (int i = 0; i < 16; ++i) { acc0[i] = 0.f; acc1[i] = 0.f; }

        #pragma unroll
        for (int kt = 0; kt < 4; ++kt) {
            float* fr = s ? f1[kt] : f0[kt];
            uintx4 u;
            u.x = pack_trunc(fr[0], fr[1]);
            u.y = pack_trunc(fr[2], fr[3]);
            u.z = pack_trunc(fr[4], fr[5]);
            u.w = pack_trunc(fr[6], fr[7]);
            short8 bfr = *(short8*)&u;
            acc0 = __builtin_amdgcn_mfma_f32_32x32x16_bf16(afr0[kt], bfr, acc0, 0, 0, 0);
            acc1 = __builtin_amdgcn_mfma_f32_32x32x16_bf16(afr1[kt], bfr, acc1, 0, 0, 0);
        }

        // epilogue: oc = oct*32 + g*8 + h*4 + i, value acc[g*4+i];
        // chunk = oct*4 + g, j = h*4 + i -> wave store = contiguous 512 B
        #pragma unroll
        for (int oct = 0; oct < 2; ++oct) {
            #pragma unroll
            for (int g = 0; g < 4; ++g) {
                floatx4 sh4 = *(const floatx4*)&shs[oct * 32 + g * 8 + h * 4];
                float v0 = (oct ? acc1[g * 4 + 0] : acc0[g * 4 + 0]) + sh4[0]; v0 = v0 > 0.f ? v0 : 0.f;
                float v1 = (oct ? acc1[g * 4 + 1] : acc0[g * 4 + 1]) + sh4[1]; v1 = v1 > 0.f ? v1 : 0.f;
                float v2 = (oct ? acc1[g * 4 + 2] : acc0[g * 4 + 2]) + sh4[2]; v2 = v2 > 0.f ? v2 : 0.f;
                float v3 = (oct ? acc1[g * 4 + 3] : acc0[g * 4 + 3]) + sh4[3]; v3 = v3 > 0.f ? v3 : 0.f;
                uintx2 st;
                st.x = pack_rne(v0, v1);
                st.y = pack_rne(v2, v3);
                const int chunk = oct * 4 + g;
                *(uintx2*)(node0 + ((size_t)(b * 8 + chunk) * HWn + p0 + s * 32 + n) * 8 + h * 4) = st;
            }
        }
    }
}

// ---------------------------------------------------------------------------
// K23: fused pools + conv2. Block = (b, 7-row band), 1024 thr = 16 waves.
// Two pool->conv2 passes (4+3 rows) over a 4-row catl (58 KB LDS) ->
// 2 blocks/CU resident, 8 waves/SIMD, 512 blocks all co-resident (no tail).
// Pool = round-3/6 verified shuffle-window code (global node0, 2-deep
// prefetch); pass structure = round-5 verified (nr=4,3); conv2 = verified
// k-slot mapping.
// ---------------------------------------------------------------------------
__global__ __launch_bounds__(1024, 8) void k23_fused(
    const unsigned short* __restrict__ node0,
    const float* __restrict__ w2,
    const float* __restrict__ bg, const float* __restrict__ bb,
    const float* __restrict__ bm, const float* __restrict__ bv,
    float* __restrict__ out)
{
    __shared__ __align__(16) unsigned short catl[16 * SLAB];  // 57.9 KB
    const int tid = threadIdx.x;
    const int lane = tid & 63;
    const int wv = tid >> 6;            // 0..15

    // XCD swizzle (512 = 8*64): XCD x owns images 8x..8x+7 (matches k1).
    const int bid = blockIdx.x;
    const int xcd = bid & 7;
    const int jj = bid >> 3;            // 0..63
    const int b = xcd * 8 + (jj >> 3);
    const int band = jj & 7;
    const int lo = band * RB;

    // pool lane geometry (verified round-3 mapping)
    const int chunk = wv >> 1;
    const int c0 = (wv & 1) * 28;
    const int local = lane >> 1;        // 0..31; computed cols = locals 2..29
    const int col = c0 - 2 + local;
    const int jh = lane & 1;            // 4-channel half
    const bool colok = (unsigned)col < (unsigned)Wn;
    const bool stcol = (local >= 2) & (local <= 29);
    const unsigned short* base = node0 + ((size_t)(b * 8 + chunk) * HWn) * 8 + jh * 4;
    unsigned short* cav = catl + (size_t)(chunk * 2) * SLAB + jh * 4;
    unsigned short* cmx = cav + SLAB;
    const uintx2 zz = (uintx2){0u, 0u};

    // ---- w2 frags (k-slot layout) + bn2 constants ----
    const int m16 = lane & 15;
    const int q = lane >> 4;
    const int t = wv & 3;               // oc-tile
    const int e = wv >> 2;              // px-tile base
    short8 afr[4];
    #pragma unroll
    for (int cp = 0; cp < 4; ++cp) {
        const int c = 2 * cp + (q >> 1);
        const int chb = ((q & 1) ? 64 : 0) + 8 * c;   // k-slot -> cat channel base
        const float* wp = w2 + (size_t)(t * 16 + m16) * 128 + chb;
        floatx4 f0 = *(const floatx4*)wp;
        floatx4 f1 = *(const floatx4*)(wp + 4);
        uintx4 u;
        u.x = pack_rne(f0[0], f0[1]);
        u.y = pack_rne(f0[2], f0[3]);
        u.z = pack_rne(f1[0], f1[1]);
        u.w = pack_rne(f1[2], f1[3]);
        afr[cp] = *(short8*)&u;
    }
    const int oc0 = t * 16 + q * 4;     // this lane's 4 output channels
    floatx4 g4 = *(const floatx4*)(bg + oc0);
    floatx4 bb4 = *(const floatx4*)(bb + oc0);
    floatx4 mm4 = *(const floatx4*)(bm + oc0);
    floatx4 vv4 = *(const floatx4*)(bv + oc0);
    float sc2[4], sh2[4];
    #pragma unroll
    for (int r = 0; r < 4; ++r) {
        sc2[r] = g4[r] * rsqrtf(vv4[r] + EPS);
        sh2[r] = bb4[r] - mm4[r] * sc2[r];
    }
    float* ob = out + (size_t)(b * 64 + oc0) * HWn;

    for (int p = 0; p < 2; ++p) {
        const int lop = lo + 4 * p;
        const int nr = p ? (RB - 4) : 4;           // 4 then 3 output rows

        // ---- pool pass into catl (fresh window state per pass) ----
        {
            auto loadrow = [&](int r) -> uintx2 {
                if ((!colok) | ((unsigned)r >= (unsigned)Hn)) return zz;
                return *(const uintx2*)(base + (size_t)(r * Wn + col) * 8);
            };
            float hs1[4], hs2[4];
            #pragma unroll
            for (int c = 0; c < 4; ++c) hs1[c] = hs2[c] = 0.f;
            uintx2 h5a = zz, h5b = zz, h5c = zz, h5d = zz, nh1 = zz, nh2 = zz;

            uintx2 cur = loadrow(lop - 2);
            uintx2 nxt = loadrow(lop - 1);

            for (int i = 0; i < nr + 4; ++i) {
                const int r = lop - 2 + i;
                uintx2 nx2 = (i < nr + 2) ? loadrow(r + 2) : zz;   // 2-deep prefetch

                // column taps via even-delta shuffles (jh parity preserved)
                uintx2 D0, D1, D3, D4;
                #pragma unroll
                for (int w = 0; w < 2; ++w) {
                    unsigned u = cur[w];
                    D1[w] = __shfl_up(u, 2);
                    D0[w] = __shfl_up(u, 4);
                    D3[w] = __shfl_down(u, 2);
                    D4[w] = __shfl_down(u, 4);
                }

                uintx2 hm5 = pmax2(pmax2(pmax2(D0, D1), pmax2(cur, D3)), D4);
                uintx2 m5 = pmax2(pmax2(pmax2(h5a, h5b), pmax2(h5c, h5d)), hm5);
                h5a = h5b; h5b = h5c; h5c = h5d; h5d = hm5;

                float a2[4];
                #pragma unroll
                for (int w = 0; w < 2; ++w) {
                    float s0 = bf_lo(D1[w]) + bf_lo(cur[w]) + bf_lo(D3[w]);
                    float s1 = bf_hi(D1[w]) + bf_hi(cur[w]) + bf_hi(D3[w]);
                    a2[w * 2 + 0] = (hs2[w * 2 + 0] + hs1[w * 2 + 0] + s0) * (1.f / 9.f);
                    a2[w * 2 + 1] = (hs2[w * 2 + 1] + hs1[w * 2 + 1] + s1) * (1.f / 9.f);
                    hs2[w * 2 + 0] = hs1[w * 2 + 0]; hs1[w * 2 + 0] = s0;
                    hs2[w * 2 + 1] = hs1[w * 2 + 1]; hs1[w * 2 + 1] = s1;
                }
                uintx2 ap;
                ap.x = pack_rne(a2[0], a2[1]);
                ap.y = pack_rne(a2[2], a2[3]);

                uintx2 al, ar;
                #pragma unroll
                for (int w = 0; w < 2; ++w) {
                    al[w] = __shfl_up(ap[w], 2);
                    ar[w] = __shfl_down(ap[w], 2);
                }
                uintx2 nh = pmax2(pmax2(al, ap), ar);
                uintx2 m3 = pmax2(pmax2(nh2, nh1), nh);
                nh2 = nh1; nh1 = nh;

                const int r2 = r - 1, r3 = r - 2;
                if (stcol && i >= 3 && i <= nr + 2)
                    *(uintx2*)(cav + (size_t)((r2 - lop) * Wn + col) * 8) = ap;
                if (stcol && i >= 4) {
                    uintx2 st;
                    st.x = pack_rne(bf_lo(m5.x) + bf_lo(m3.x), bf_hi(m5.x) + bf_hi(m3.x));
                    st.y = pack_rne(bf_lo(m5.y) + bf_lo(m3.y), bf_hi(m5.y) + bf_hi(m3.y));
                    *(uintx2*)(cmx + (size_t)((r3 - lop) * Wn + col) * 8) = st;
                }
                cur = nxt; nxt = nx2;
            }
        }
        __syncthreads();                 // catl ready

        // ---- conv2 on nr rows (nr*56 px) ----
        const int npxc = nr * Wn;                 // 224 or 168
        const int nPT = (npxc + 15) >> 4;         // 14 or 11 px-tiles
        for (int k = 0; k < 4; ++k) {
            const int pt = e + 4 * k;
            if (pt >= nPT) break;
            const int px = pt * 16 + m16;
            floatx4 acc = (floatx4){0.f, 0.f, 0.f, 0.f};
            #pragma unroll
            for (int cp = 0; cp < 4; ++cp) {
                // slab = 4*cp + q: quads at bank offsets {0,8,16,24} -> 2-way
                short8 bfr = *(const short8*)(catl + (size_t)(4 * cp + q) * SLAB + (size_t)px * 8);
                acc = __builtin_amdgcn_mfma_f32_16x16x32_bf16(afr[cp], bfr, acc, 0, 0, 0);
            }
            if (px < npxc) {
                #pragma unroll
                for (int r = 0; r < 4; ++r) {
                    float v = fmaf(acc[r], sc2[r], sh2[r]);
                    ob[(size_t)r * HWn + lop * Wn + px] = v > 0.f ? v : 0.f;
                }
            }
        }
        __syncthreads();                 // catl consumed before next pass pool
    }
}

extern "C" void kernel_launch(void* const* d_in, const int* in_sizes, int n_in,
                              void* d_out, int out_size, void* d_ws, size_t ws_size,
                              hipStream_t stream)
{
    const float* x   = (const float*)d_in[0];
    const float* w1  = (const float*)d_in[1];
    const float* w2  = (const float*)d_in[2];
    const float* b1g = (const float*)d_in[3];
    const float* b1b = (const float*)d_in[4];
    const float* b1m = (const float*)d_in[5];
    const float* b1v = (const float*)d_in[6];
    const float* b2g = (const float*)d_in[7];
    const float* b2b = (const float*)d_in[8];
    const float* b2m = (const float*)d_in[9];
    const float* b2v = (const float*)d_in[10];

    float* out = (float*)d_out;
    unsigned short* node0 = (unsigned short*)d_ws;            // 25.7 MB

    k1_conv1<<<dim3(784), dim3(256), 0, stream>>>(x, w1, b1g, b1b, b1m, b1v, node0);
    k23_fused<<<dim3(Bn * NBAND), dim3(1024), 0, stream>>>(node0, w2, b2g, b2b, b2m, b2v, out);
}

// Round 8
// 180.817 us; speedup vs baseline: 1.4271x; 1.4271x over previous
//
#include <hip/hip_runtime.h>
#include <cstddef>

#define EPS 1e-5f
static constexpr int Bn = 64, Cn = 64, Hn = 56, Wn = 56, HWn = Hn * Wn; // 3136
static constexpr int RB = 7;          // output rows per band in k23
static constexpr int NBAND = 8;       // 56/7 -> 512 blocks = 2/CU resident, zero tail
static constexpr int SLAB = 1808;     // cat slab: 224*8+16 ushorts (904 dw % 32 == 8 -> quad bank offs {0,8,16,24})

typedef __attribute__((ext_vector_type(8))) short short8;
typedef __attribute__((ext_vector_type(8))) unsigned short ushort8;
typedef __attribute__((ext_vector_type(4))) float floatx4;
typedef __attribute__((ext_vector_type(16))) float floatx16;
typedef __attribute__((ext_vector_type(4))) unsigned int uintx4;
typedef __attribute__((ext_vector_type(2))) unsigned int uintx2;

__device__ __forceinline__ unsigned pack_rne(float a, float b) {
    unsigned ua = __float_as_uint(a), ub = __float_as_uint(b);
    ua = ua + 0x7fffu + ((ua >> 16) & 1u);
    ub = ub + 0x7fffu + ((ub >> 16) & 1u);
    return __builtin_amdgcn_perm(ub, ua, 0x07060302);
}
__device__ __forceinline__ unsigned pack_trunc(float a, float b) {
    return __builtin_amdgcn_perm(__float_as_uint(b), __float_as_uint(a), 0x07060302);
}
__device__ __forceinline__ ushort8 pmax(ushort8 a, ushort8 b) {
    return __builtin_elementwise_max(a, b);   // valid bf16 max for values >= 0
}
__device__ __forceinline__ float bf_lo(unsigned u) { return __uint_as_float(u << 16); }
__device__ __forceinline__ float bf_hi(unsigned u) { return __uint_as_float(u & 0xffff0000u); }

// Layouts (bf16):
//   node0: [b][chunk=8][px=3136][j=8]
//   cat (LDS, per 4-row pass): 16 slabs of SLAB ushorts; slab = chunk*2 + plane
//     (plane 0 = avg, 1 = maxsum), element [px_local<=224][j=8]

// ---------------------------------------------------------------------------
// K1: node0 = relu(bn1(conv1x1(x,w1))), 32x32x16 MFMA, direct global B loads,
// all 64 loads issued up front. XCD swizzle: XCD x computes images 8x..8x+7
// (matches k23's read set -> node0 write+read stays in the local 4MB L2).
// launch_bounds(256,3): 3 blocks/CU resident. Verbatim round-7 (passed).
// ---------------------------------------------------------------------------
__global__ __launch_bounds__(256, 3) void k1_conv1(
    const float* __restrict__ x, const float* __restrict__ w1,
    const float* __restrict__ bg, const float* __restrict__ bb,
    const float* __restrict__ bm, const float* __restrict__ bv,
    unsigned short* __restrict__ node0)
{
    __shared__ float scs[64], shs[64];
    const int tid = threadIdx.x;
    if (tid < 64) {
        float sc = bg[tid] * rsqrtf(bv[tid] + EPS);
        scs[tid] = sc;
        shs[tid] = bb[tid] - bm[tid] * sc;
    }
    __syncthreads();
    const int lane = tid & 63;
    const int wv   = tid >> 6;
    const int n    = lane & 31;
    const int h    = lane >> 5;

    // A-frags: w1[oc = oct*32+n][kt*16 + h*8 + 0..7] * sc[oc]
    short8 afr0[4], afr1[4];
    {
        const float s0 = scs[n], s1 = scs[32 + n];
        #pragma unroll
        for (int kt = 0; kt < 4; ++kt) {
            const float* wp0 = w1 + (size_t)n * 64 + kt * 16 + h * 8;
            floatx4 f0 = *(const floatx4*)wp0;
            floatx4 f1 = *(const floatx4*)(wp0 + 4);
            uintx4 u;
            u.x = pack_rne(f0[0] * s0, f0[1] * s0);
            u.y = pack_rne(f0[2] * s0, f0[3] * s0);
            u.z = pack_rne(f1[0] * s0, f1[1] * s0);
            u.w = pack_rne(f1[2] * s0, f1[3] * s0);
            afr0[kt] = *(short8*)&u;
            const float* wp1 = wp0 + 32 * 64;
            floatx4 g0 = *(const floatx4*)wp1;
            floatx4 g1 = *(const floatx4*)(wp1 + 4);
            uintx4 v;
            v.x = pack_rne(g0[0] * s1, g0[1] * s1);
            v.y = pack_rne(g0[2] * s1, g0[3] * s1);
            v.z = pack_rne(g1[0] * s1, g1[1] * s1);
            v.w = pack_rne(g1[2] * s1, g1[3] * s1);
            afr1[kt] = *(short8*)&v;
        }
    }

    // XCD-matched block swizzle: XCD x covers px slice of images 8x..8x+7.
    const int bid = blockIdx.x;
    const int xcd = bid & 7;
    const int idx = bid >> 3;                     // 0..97
    const int P = (xcd * 98 + idx) * 256 + wv * 64;
    const int b = P / HWn, p0 = P - b * HWn;      // 64 | 3136: no image crossing
    const float* xb = x + (size_t)b * 64 * HWn + p0 + n;

    // issue ALL 64 B-operand loads up front (16 KB/wave in flight)
    float f0[4][8], f1[4][8];
    #pragma unroll
    for (int kt = 0; kt < 4; ++kt)
        #pragma unroll
        for (int j = 0; j < 8; ++j) {
            const float* xp = xb + (size_t)(kt * 16 + h * 8 + j) * HWn;
            f0[kt][j] = xp[0];
            f1[kt][j] = xp[32];
        }

    #pragma unroll
    for (int s = 0; s < 2; ++s) {
        floatx16 acc0, acc1;
        #pragma unroll
        for (int i = 0; i < 16; ++i) { acc0[i] = 0.f; acc1[i] = 0.f; }

        #pragma unroll
        for (int kt = 0; kt < 4; ++kt) {
            float* fr = s ? f1[kt] : f0[kt];
            uintx4 u;
            u.x = pack_trunc(fr[0], fr[1]);
            u.y = pack_trunc(fr[2], fr[3]);
            u.z = pack_trunc(fr[4], fr[5]);
            u.w = pack_trunc(fr[6], fr[7]);
            short8 bfr = *(short8*)&u;
            acc0 = __builtin_amdgcn_mfma_f32_32x32x16_bf16(afr0[kt], bfr, acc0, 0, 0, 0);
            acc1 = __builtin_amdgcn_mfma_f32_32x32x16_bf16(afr1[kt], bfr, acc1, 0, 0, 0);
        }

        // epilogue: oc = oct*32 + g*8 + h*4 + i, value acc[g*4+i];
        // chunk = oct*4 + g, j = h*4 + i -> wave store = contiguous 512 B
        #pragma unroll
        for (int oct = 0; oct < 2; ++oct) {
            #pragma unroll
            for (int g = 0; g < 4; ++g) {
                floatx4 sh4 = *(const floatx4*)&shs[oct * 32 + g * 8 + h * 4];
                float v0 = (oct ? acc1[g * 4 + 0] : acc0[g * 4 + 0]) + sh4[0]; v0 = v0 > 0.f ? v0 : 0.f;
                float v1 = (oct ? acc1[g * 4 + 1] : acc0[g * 4 + 1]) + sh4[1]; v1 = v1 > 0.f ? v1 : 0.f;
                float v2 = (oct ? acc1[g * 4 + 2] : acc0[g * 4 + 2]) + sh4[2]; v2 = v2 > 0.f ? v2 : 0.f;
                float v3 = (oct ? acc1[g * 4 + 3] : acc0[g * 4 + 3]) + sh4[3]; v3 = v3 > 0.f ? v3 : 0.f;
                uintx2 st;
                st.x = pack_rne(v0, v1);
                st.y = pack_rne(v2, v3);
                const int chunk = oct * 4 + g;
                *(uintx2*)(node0 + ((size_t)(b * 8 + chunk) * HWn + p0 + s * 32 + n) * 8 + h * 4) = st;
            }
        }
    }
}

// ---------------------------------------------------------------------------
// K23: fused pools + conv2. Block = (b, 7-row band), 512 thr = 8 waves.
// Two pool->conv2 passes (4+3 rows) over a 4-row catl (58 KB LDS).
// launch_bounds(512,4): VGPR cap 128 (demand ~100, no spill) -> with 58 KB
// LDS the scheduler fits 2 blocks/CU: all 512 blocks co-resident (zero tail)
// and one block's pool-load phase overlaps the other's MFMA phase.
// Pool = round-2's measured-and-passed per-wave-chunk ushort8 window code
// (odd-delta shfl taps, edge masks) + 2-deep prefetch; conv2 = verified
// k-slot mapping.
// ---------------------------------------------------------------------------
__global__ __launch_bounds__(512, 4) void k23_fused(
    const unsigned short* __restrict__ node0,
    const float* __restrict__ w2,
    const float* __restrict__ bg, const float* __restrict__ bb,
    const float* __restrict__ bm, const float* __restrict__ bv,
    float* __restrict__ out)
{
    __shared__ __align__(16) unsigned short catl[16 * SLAB];  // 57.9 KB
    const int tid = threadIdx.x;
    const int lane = tid & 63;
    const int wv = tid >> 6;            // 0..7

    // XCD swizzle (512 = 8*64): XCD x owns images 8x..8x+7 (matches k1).
    const int bid = blockIdx.x;
    const int xcd = bid & 7;
    const int jj = bid >> 3;            // 0..63
    const int b = xcd * 8 + (jj >> 3);
    const int band = jj & 7;
    const int lo = band * RB;

    // pool lane geometry (round-2 verified): wave = chunk, lane = col
    const int chunk = wv;
    const int col = lane;
    const bool act = col < Wn;
    const unsigned short* base = node0 + ((size_t)(b * 8 + chunk) * HWn) * 8;
    unsigned short* cav = catl + (size_t)(chunk * 2 + 0) * SLAB;
    unsigned short* cmx = catl + (size_t)(chunk * 2 + 1) * SLAB;
    const ushort8 zz = (ushort8)0;

    // ---- w2 frags (k-slot layout) + bn2 constants ----
    const int m16 = lane & 15;
    const int q = lane >> 4;
    const int t = wv & 3;               // oc-tile
    const int e = wv >> 2;              // px-parity (0/1)
    short8 afr[4];
    #pragma unroll
    for (int cp = 0; cp < 4; ++cp) {
        const int c = 2 * cp + (q >> 1);
        const int chb = ((q & 1) ? 64 : 0) + 8 * c;   // k-slot -> cat channel base
        const float* wp = w2 + (size_t)(t * 16 + m16) * 128 + chb;
        floatx4 f0 = *(const floatx4*)wp;
        floatx4 f1 = *(const floatx4*)(wp + 4);
        uintx4 u;
        u.x = pack_rne(f0[0], f0[1]);
        u.y = pack_rne(f0[2], f0[3]);
        u.z = pack_rne(f1[0], f1[1]);
        u.w = pack_rne(f1[2], f1[3]);
        afr[cp] = *(short8*)&u;
    }
    const int oc0 = t * 16 + q * 4;     // this lane's 4 output channels
    floatx4 g4 = *(const floatx4*)(bg + oc0);
    floatx4 bb4 = *(const floatx4*)(bb + oc0);
    floatx4 mm4 = *(const floatx4*)(bm + oc0);
    floatx4 vv4 = *(const floatx4*)(bv + oc0);
    float sc2[4], sh2[4];
    #pragma unroll
    for (int r = 0; r < 4; ++r) {
        sc2[r] = g4[r] * rsqrtf(vv4[r] + EPS);
        sh2[r] = bb4[r] - mm4[r] * sc2[r];
    }
    float* ob = out + (size_t)(b * 64 + oc0) * HWn;

    for (int p = 0; p < 2; ++p) {
        const int lop = lo + 4 * p;
        const int nr = p ? (RB - 4) : 4;           // 4 then 3 output rows

        // ---- pool pass into catl (fresh window state per pass) ----
        {
            auto loadrow = [&](int r) -> ushort8 {
                bool ok = act && ((unsigned)r < (unsigned)Hn);
                return ok ? *(const ushort8*)(base + (size_t)(r * Wn + col) * 8) : zz;
            };

            float hs1[8], hs2[8];
            #pragma unroll
            for (int j = 0; j < 8; ++j) hs1[j] = hs2[j] = 0.f;
            ushort8 h5a = zz, h5b = zz, h5c = zz, h5d = zz, nh1 = zz, nh2 = zz;

            ushort8 cur = loadrow(lop - 2);
            ushort8 nxt = loadrow(lop - 1);

            for (int i = 0; i < nr + 4; ++i) {
                const int r = lop - 2 + i;
                ushort8 nx2 = (i < nr + 2) ? loadrow(r + 2) : zz;  // 2-deep prefetch

                // column taps via shuffles (lanes >=56 hold zz -> right edge 0)
                const uintx4 uc = *(const uintx4*)&cur;
                uintx4 t0, t1, t3, t4;
                #pragma unroll
                for (int w = 0; w < 4; ++w) {
                    unsigned u = uc[w];
                    unsigned l1 = __shfl_up(u, 1);
                    unsigned l2 = __shfl_up(u, 2);
                    unsigned r1 = __shfl_down(u, 1);
                    unsigned r2v = __shfl_down(u, 2);
                    t0[w] = (lane < 2) ? 0u : l2;
                    t1[w] = (lane < 1) ? 0u : l1;
                    t3[w] = r1;
                    t4[w] = r2v;
                }
                const ushort8 D0 = *(const ushort8*)&t0;
                const ushort8 D1 = *(const ushort8*)&t1;
                const ushort8 D3 = *(const ushort8*)&t3;
                const ushort8 D4 = *(const ushort8*)&t4;

                ushort8 hm5 = pmax(pmax(pmax(D0, D1), pmax(cur, D3)), D4);
                ushort8 m5 = pmax(pmax(pmax(h5a, h5b), pmax(h5c, h5d)), hm5);
                h5a = h5b; h5b = h5c; h5c = h5d; h5d = hm5;

                const uintx4 ul = t1;
                const uintx4 ur = t3;
                float a2[8];
                const int r2 = r - 1, r3 = r - 2;
                const bool v2 = ((unsigned)r2 < (unsigned)Hn) && act; // lane56 ap stays 0
                #pragma unroll
                for (int w = 0; w < 4; ++w) {
                    float hsum0 = bf_lo(ul[w]) + bf_lo(uc[w]) + bf_lo(ur[w]);
                    float hsum1 = bf_hi(ul[w]) + bf_hi(uc[w]) + bf_hi(ur[w]);
                    a2[w * 2 + 0] = v2 ? (hs2[w * 2 + 0] + hs1[w * 2 + 0] + hsum0) * (1.f / 9.f) : 0.f;
                    a2[w * 2 + 1] = v2 ? (hs2[w * 2 + 1] + hs1[w * 2 + 1] + hsum1) * (1.f / 9.f) : 0.f;
                    hs2[w * 2 + 0] = hs1[w * 2 + 0]; hs1[w * 2 + 0] = hsum0;
                    hs2[w * 2 + 1] = hs1[w * 2 + 1]; hs1[w * 2 + 1] = hsum1;
                }
                uintx4 ap;
                ap.x = pack_rne(a2[0], a2[1]);
                ap.y = pack_rne(a2[2], a2[3]);
                ap.z = pack_rne(a2[4], a2[5]);
                ap.w = pack_rne(a2[6], a2[7]);
                uintx4 al, ar;
                #pragma unroll
                for (int w = 0; w < 4; ++w) {
                    unsigned u = ap[w];
                    unsigned lu = __shfl_up(u, 1);
                    unsigned ru = __shfl_down(u, 1);
                    al[w] = (lane == 0) ? 0u : lu;
                    ar[w] = (lane == 63) ? 0u : ru;
                }
                ushort8 nh = pmax(pmax(*(ushort8*)&al, *(ushort8*)&ap), *(ushort8*)&ar);
                ushort8 m3 = pmax(pmax(nh2, nh1), nh);
                nh2 = nh1; nh1 = nh;

                if (act && i >= 3 && i <= nr + 2)
                    *(uintx4*)(cav + (size_t)((r2 - lop) * Wn + col) * 8) = ap;
                if (act && i >= 4) {
                    const uintx4 u5 = *(const uintx4*)&m5;
                    const uintx4 u3 = *(const uintx4*)&m3;
                    uintx4 st;
                    #pragma unroll
                    for (int w = 0; w < 4; ++w)
                        st[w] = pack_rne(bf_lo(u5[w]) + bf_lo(u3[w]), bf_hi(u5[w]) + bf_hi(u3[w]));
                    *(uintx4*)(cmx + (size_t)((r3 - lop) * Wn + col) * 8) = st;
                }
                cur = nxt; nxt = nx2;
            }
        }
        __syncthreads();                 // catl ready

        // ---- conv2 on nr rows (nr*56 px) ----
        const int npxc = nr * Wn;                 // 224 or 168
        const int nPT = (npxc + 15) >> 4;         // 14 or 11 px-tiles
        for (int k = 0; k < 7; ++k) {
            const int pt = e + 2 * k;             // interleaved for pass-1 balance
            if (pt >= nPT) break;
            const int px = pt * 16 + m16;
            floatx4 acc = (floatx4){0.f, 0.f, 0.f, 0.f};
            #pragma unroll
            for (int cp = 0; cp < 4; ++cp) {
                // slab = 4*cp + q: quads at bank offsets {0,8,16,24} -> 2-way
                short8 bfr = *(const short8*)(catl + (size_t)(4 * cp + q) * SLAB + (size_t)px * 8);
                acc = __builtin_amdgcn_mfma_f32_16x16x32_bf16(afr[cp], bfr, acc, 0, 0, 0);
            }
            if (px < npxc) {
                #pragma unroll
                for (int r = 0; r < 4; ++r) {
                    float v = fmaf(acc[r], sc2[r], sh2[r]);
                    ob[(size_t)r * HWn + lop * Wn + px] = v > 0.f ? v : 0.f;
                }
            }
        }
        __syncthreads();                 // catl consumed before next pass pool
    }
}

extern "C" void kernel_launch(void* const* d_in, const int* in_sizes, int n_in,
                              void* d_out, int out_size, void* d_ws, size_t ws_size,
                              hipStream_t stream)
{
    const float* x   = (const float*)d_in[0];
    const float* w1  = (const float*)d_in[1];
    const float* w2  = (const float*)d_in[2];
    const float* b1g = (const float*)d_in[3];
    const float* b1b = (const float*)d_in[4];
    const float* b1m = (const float*)d_in[5];
    const float* b1v = (const float*)d_in[6];
    const float* b2g = (const float*)d_in[7];
    const float* b2b = (const float*)d_in[8];
    const float* b2m = (const float*)d_in[9];
    const float* b2v = (const float*)d_in[10];

    float* out = (float*)d_out;
    unsigned short* node0 = (unsigned short*)d_ws;            // 25.7 MB

    k1_conv1<<<dim3(784), dim3(256), 0, stream>>>(x, w1, b1g, b1b, b1m, b1v, node0);
    k23_fused<<<dim3(Bn * NBAND), dim3(512), 0, stream>>>(node0, w2, b2g, b2b, b2m, b2v, out);
}

// Round 9
// 162.746 us; speedup vs baseline: 1.5856x; 1.1110x over previous
//
#include <hip/hip_runtime.h>
#include <cstddef>

#define EPS 1e-5f
static constexpr int Bn = 64, Cn = 64, Hn = 56, Wn = 56, HWn = Hn * Wn; // 3136
static constexpr int RB = 7;          // output rows per band in k23
static constexpr int NBAND = 8;       // 56/7 -> 512 blocks = 2/CU resident, zero tail
static constexpr int SLAB = 1808;     // cat slab: 224*8+16 ushorts (904 dw % 32 == 8 -> quad bank offs {0,8,16,24})

typedef __attribute__((ext_vector_type(8))) short short8;
typedef __attribute__((ext_vector_type(8))) unsigned short ushort8;
typedef __attribute__((ext_vector_type(4))) float floatx4;
typedef __attribute__((ext_vector_type(16))) float floatx16;
typedef __attribute__((ext_vector_type(4))) unsigned int uintx4;
typedef __attribute__((ext_vector_type(2))) unsigned int uintx2;

__device__ __forceinline__ unsigned pack_rne(float a, float b) {
    unsigned ua = __float_as_uint(a), ub = __float_as_uint(b);
    ua = ua + 0x7fffu + ((ua >> 16) & 1u);
    ub = ub + 0x7fffu + ((ub >> 16) & 1u);
    return __builtin_amdgcn_perm(ub, ua, 0x07060302);
}
__device__ __forceinline__ unsigned pack_trunc(float a, float b) {
    return __builtin_amdgcn_perm(__float_as_uint(b), __float_as_uint(a), 0x07060302);
}
__device__ __forceinline__ ushort8 pmax(ushort8 a, ushort8 b) {
    return __builtin_elementwise_max(a, b);   // valid bf16 max for values >= 0
}
__device__ __forceinline__ float bf_lo(unsigned u) { return __uint_as_float(u << 16); }
__device__ __forceinline__ float bf_hi(unsigned u) { return __uint_as_float(u & 0xffff0000u); }

// Layouts (bf16):
//   node0: [b][chunk=8][px=3136][j=8]
//   cat (LDS, per 4-row pass): 16 slabs of SLAB ushorts; slab = chunk*2 + plane
//     (plane 0 = avg, 1 = maxsum), element [px_local<=224][j=8]

// ---------------------------------------------------------------------------
// K1: node0 = relu(bn1(conv1x1(x,w1))), 32x32x16 MFMA, direct global B loads,
// all 64 loads issued up front. XCD swizzle: XCD x computes images 8x..8x+7
// (matches k23's read set -> node0 write+read stays in the local 4MB L2).
// (256,3): cap ~170 VGPR under either launch_bounds semantics; demand ~150.
// Verbatim round-7/8 (passed).
// ---------------------------------------------------------------------------
__global__ __launch_bounds__(256, 3) void k1_conv1(
    const float* __restrict__ x, const float* __restrict__ w1,
    const float* __restrict__ bg, const float* __restrict__ bb,
    const float* __restrict__ bm, const float* __restrict__ bv,
    unsigned short* __restrict__ node0)
{
    __shared__ float scs[64], shs[64];
    const int tid = threadIdx.x;
    if (tid < 64) {
        float sc = bg[tid] * rsqrtf(bv[tid] + EPS);
        scs[tid] = sc;
        shs[tid] = bb[tid] - bm[tid] * sc;
    }
    __syncthreads();
    const int lane = tid & 63;
    const int wv   = tid >> 6;
    const int n    = lane & 31;
    const int h    = lane >> 5;

    // A-frags: w1[oc = oct*32+n][kt*16 + h*8 + 0..7] * sc[oc]
    short8 afr0[4], afr1[4];
    {
        const float s0 = scs[n], s1 = scs[32 + n];
        #pragma unroll
        for (int kt = 0; kt < 4; ++kt) {
            const float* wp0 = w1 + (size_t)n * 64 + kt * 16 + h * 8;
            floatx4 f0 = *(const floatx4*)wp0;
            floatx4 f1 = *(const floatx4*)(wp0 + 4);
            uintx4 u;
            u.x = pack_rne(f0[0] * s0, f0[1] * s0);
            u.y = pack_rne(f0[2] * s0, f0[3] * s0);
            u.z = pack_rne(f1[0] * s0, f1[1] * s0);
            u.w = pack_rne(f1[2] * s0, f1[3] * s0);
            afr0[kt] = *(short8*)&u;
            const float* wp1 = wp0 + 32 * 64;
            floatx4 g0 = *(const floatx4*)wp1;
            floatx4 g1 = *(const floatx4*)(wp1 + 4);
            uintx4 v;
            v.x = pack_rne(g0[0] * s1, g0[1] * s1);
            v.y = pack_rne(g0[2] * s1, g0[3] * s1);
            v.z = pack_rne(g1[0] * s1, g1[1] * s1);
            v.w = pack_rne(g1[2] * s1, g1[3] * s1);
            afr1[kt] = *(short8*)&v;
        }
    }

    // XCD-matched block swizzle: XCD x covers px slice of images 8x..8x+7.
    const int bid = blockIdx.x;
    const int xcd = bid & 7;
    const int idx = bid >> 3;                     // 0..97
    const int P = (xcd * 98 + idx) * 256 + wv * 64;
    const int b = P / HWn, p0 = P - b * HWn;      // 64 | 3136: no image crossing
    const float* xb = x + (size_t)b * 64 * HWn + p0 + n;

    // issue ALL 64 B-operand loads up front (16 KB/wave in flight)
    float f0[4][8], f1[4][8];
    #pragma unroll
    for (int kt = 0; kt < 4; ++kt)
        #pragma unroll
        for (int j = 0; j < 8; ++j) {
            const float* xp = xb + (size_t)(kt * 16 + h * 8 + j) * HWn;
            f0[kt][j] = xp[0];
            f1[kt][j] = xp[32];
        }

    #pragma unroll
    for (int s = 0; s < 2; ++s) {
        floatx16 acc0, acc1;
        #pragma unroll
        for (int i = 0; i < 16; ++i) { acc0[i] = 0.f; acc1[i] = 0.f; }

        #pragma unroll
        for (int kt = 0; kt < 4; ++kt) {
            float* fr = s ? f1[kt] : f0[kt];
            uintx4 u;
            u.x = pack_trunc(fr[0], fr[1]);
            u.y = pack_trunc(fr[2], fr[3]);
            u.z = pack_trunc(fr[4], fr[5]);
            u.w = pack_trunc(fr[6], fr[7]);
            short8 bfr = *(short8*)&u;
            acc0 = __builtin_amdgcn_mfma_f32_32x32x16_bf16(afr0[kt], bfr, acc0, 0, 0, 0);
            acc1 = __builtin_amdgcn_mfma_f32_32x32x16_bf16(afr1[kt], bfr, acc1, 0, 0, 0);
        }

        // epilogue: oc = oct*32 + g*8 + h*4 + i, value acc[g*4+i];
        // chunk = oct*4 + g, j = h*4 + i -> wave store = contiguous 512 B
        #pragma unroll
        for (int oct = 0; oct < 2; ++oct) {
            #pragma unroll
            for (int g = 0; g < 4; ++g) {
                floatx4 sh4 = *(const floatx4*)&shs[oct * 32 + g * 8 + h * 4];
                float v0 = (oct ? acc1[g * 4 + 0] : acc0[g * 4 + 0]) + sh4[0]; v0 = v0 > 0.f ? v0 : 0.f;
                float v1 = (oct ? acc1[g * 4 + 1] : acc0[g * 4 + 1]) + sh4[1]; v1 = v1 > 0.f ? v1 : 0.f;
                float v2 = (oct ? acc1[g * 4 + 2] : acc0[g * 4 + 2]) + sh4[2]; v2 = v2 > 0.f ? v2 : 0.f;
                float v3 = (oct ? acc1[g * 4 + 3] : acc0[g * 4 + 3]) + sh4[3]; v3 = v3 > 0.f ? v3 : 0.f;
                uintx2 st;
                st.x = pack_rne(v0, v1);
                st.y = pack_rne(v2, v3);
                const int chunk = oct * 4 + g;
                *(uintx2*)(node0 + ((size_t)(b * 8 + chunk) * HWn + p0 + s * 32 + n) * 8 + h * 4) = st;
            }
        }
    }
}

// ---------------------------------------------------------------------------
// K23: fused pools + conv2. Block = (b, 7-row band), 512 thr = 8 waves.
// Two pool->conv2 passes (4+3 rows) over a 4-row catl (58 KB LDS).
// SINGLE CHANGE vs round 8: launch_bounds(512, 2).
// Round-7/8 evidence: this toolchain treats arg2 as CUDA min-BLOCKS-per-CU
// (alloc == 2048/(waves_per_block*arg2): (1024,8)->32, (512,4)->64 VGPR,
// both spilled). (512,2) -> cap 128 VGPR: the ~120-reg pool state fits,
// and <=128 VGPR still gives 4 waves/SIMD = 2 blocks/CU with 58 KB LDS.
// ---------------------------------------------------------------------------
__global__ __launch_bounds__(512, 2) void k23_fused(
    const unsigned short* __restrict__ node0,
    const float* __restrict__ w2,
    const float* __restrict__ bg, const float* __restrict__ bb,
    const float* __restrict__ bm, const float* __restrict__ bv,
    float* __restrict__ out)
{
    __shared__ __align__(16) unsigned short catl[16 * SLAB];  // 57.9 KB
    const int tid = threadIdx.x;
    const int lane = tid & 63;
    const int wv = tid >> 6;            // 0..7

    // XCD swizzle (512 = 8*64): XCD x owns images 8x..8x+7 (matches k1).
    const int bid = blockIdx.x;
    const int xcd = bid & 7;
    const int jj = bid >> 3;            // 0..63
    const int b = xcd * 8 + (jj >> 3);
    const int band = jj & 7;
    const int lo = band * RB;

    // pool lane geometry (round-2 verified): wave = chunk, lane = col
    const int chunk = wv;
    const int col = lane;
    const bool act = col < Wn;
    const unsigned short* base = node0 + ((size_t)(b * 8 + chunk) * HWn) * 8;
    unsigned short* cav = catl + (size_t)(chunk * 2 + 0) * SLAB;
    unsigned short* cmx = catl + (size_t)(chunk * 2 + 1) * SLAB;
    const ushort8 zz = (ushort8)0;

    // ---- w2 frags (k-slot layout) + bn2 constants ----
    const int m16 = lane & 15;
    const int q = lane >> 4;
    const int t = wv & 3;               // oc-tile
    const int e = wv >> 2;              // px-parity (0/1)
    short8 afr[4];
    #pragma unroll
    for (int cp = 0; cp < 4; ++cp) {
        const int c = 2 * cp + (q >> 1);
        const int chb = ((q & 1) ? 64 : 0) + 8 * c;   // k-slot -> cat channel base
        const float* wp = w2 + (size_t)(t * 16 + m16) * 128 + chb;
        floatx4 f0 = *(const floatx4*)wp;
        floatx4 f1 = *(const floatx4*)(wp + 4);
        uintx4 u;
        u.x = pack_rne(f0[0], f0[1]);
        u.y = pack_rne(f0[2], f0[3]);
        u.z = pack_rne(f1[0], f1[1]);
        u.w = pack_rne(f1[2], f1[3]);
        afr[cp] = *(short8*)&u;
    }
    const int oc0 = t * 16 + q * 4;     // this lane's 4 output channels
    floatx4 g4 = *(const floatx4*)(bg + oc0);
    floatx4 bb4 = *(const floatx4*)(bb + oc0);
    floatx4 mm4 = *(const floatx4*)(bm + oc0);
    floatx4 vv4 = *(const floatx4*)(bv + oc0);
    float sc2[4], sh2[4];
    #pragma unroll
    for (int r = 0; r < 4; ++r) {
        sc2[r] = g4[r] * rsqrtf(vv4[r] + EPS);
        sh2[r] = bb4[r] - mm4[r] * sc2[r];
    }
    float* ob = out + (size_t)(b * 64 + oc0) * HWn;

    for (int p = 0; p < 2; ++p) {
        const int lop = lo + 4 * p;
        const int nr = p ? (RB - 4) : 4;           // 4 then 3 output rows

        // ---- pool pass into catl (fresh window state per pass) ----
        {
            auto loadrow = [&](int r) -> ushort8 {
                bool ok = act && ((unsigned)r < (unsigned)Hn);
                return ok ? *(const ushort8*)(base + (size_t)(r * Wn + col) * 8) : zz;
            };

            float hs1[8], hs2[8];
            #pragma unroll
            for (int j = 0; j < 8; ++j) hs1[j] = hs2[j] = 0.f;
            ushort8 h5a = zz, h5b = zz, h5c = zz, h5d = zz, nh1 = zz, nh2 = zz;

            ushort8 cur = loadrow(lop - 2);
            ushort8 nxt = loadrow(lop - 1);

            for (int i = 0; i < nr + 4; ++i) {
                const int r = lop - 2 + i;
                ushort8 nx2 = (i < nr + 2) ? loadrow(r + 2) : zz;  // 2-deep prefetch

                // column taps via shuffles (lanes >=56 hold zz -> right edge 0)
                const uintx4 uc = *(const uintx4*)&cur;
                uintx4 t0, t1, t3, t4;
                #pragma unroll
                for (int w = 0; w < 4; ++w) {
                    unsigned u = uc[w];
                    unsigned l1 = __shfl_up(u, 1);
                    unsigned l2 = __shfl_up(u, 2);
                    unsigned r1 = __shfl_down(u, 1);
                    unsigned r2v = __shfl_down(u, 2);
                    t0[w] = (lane < 2) ? 0u : l2;
                    t1[w] = (lane < 1) ? 0u : l1;
                    t3[w] = r1;
                    t4[w] = r2v;
                }
                const ushort8 D0 = *(const ushort8*)&t0;
                const ushort8 D1 = *(const ushort8*)&t1;
                const ushort8 D3 = *(const ushort8*)&t3;
                const ushort8 D4 = *(const ushort8*)&t4;

                ushort8 hm5 = pmax(pmax(pmax(D0, D1), pmax(cur, D3)), D4);
                ushort8 m5 = pmax(pmax(pmax(h5a, h5b), pmax(h5c, h5d)), hm5);
                h5a = h5b; h5b = h5c; h5c = h5d; h5d = hm5;

                const uintx4 ul = t1;
                const uintx4 ur = t3;
                float a2[8];
                const int r2 = r - 1, r3 = r - 2;
                const bool v2 = ((unsigned)r2 < (unsigned)Hn) && act; // lane56 ap stays 0
                #pragma unroll
                for (int w = 0; w < 4; ++w) {
                    float hsum0 = bf_lo(ul[w]) + bf_lo(uc[w]) + bf_lo(ur[w]);
                    float hsum1 = bf_hi(ul[w]) + bf_hi(uc[w]) + bf_hi(ur[w]);
                    a2[w * 2 + 0] = v2 ? (hs2[w * 2 + 0] + hs1[w * 2 + 0] + hsum0) * (1.f / 9.f) : 0.f;
                    a2[w * 2 + 1] = v2 ? (hs2[w * 2 + 1] + hs1[w * 2 + 1] + hsum1) * (1.f / 9.f) : 0.f;
                    hs2[w * 2 + 0] = hs1[w * 2 + 0]; hs1[w * 2 + 0] = hsum0;
                    hs2[w * 2 + 1] = hs1[w * 2 + 1]; hs1[w * 2 + 1] = hsum1;
                }
                uintx4 ap;
                ap.x = pack_rne(a2[0], a2[1]);
                ap.y = pack_rne(a2[2], a2[3]);
                ap.z = pack_rne(a2[4], a2[5]);
                ap.w = pack_rne(a2[6], a2[7]);
                uintx4 al, ar;
                #pragma unroll
                for (int w = 0; w < 4; ++w) {
                    unsigned u = ap[w];
                    unsigned lu = __shfl_up(u, 1);
                    unsigned ru = __shfl_down(u, 1);
                    al[w] = (lane == 0) ? 0u : lu;
                    ar[w] = (lane == 63) ? 0u : ru;
                }
                ushort8 nh = pmax(pmax(*(ushort8*)&al, *(ushort8*)&ap), *(ushort8*)&ar);
                ushort8 m3 = pmax(pmax(nh2, nh1), nh);
                nh2 = nh1; nh1 = nh;

                if (act && i >= 3 && i <= nr + 2)
                    *(uintx4*)(cav + (size_t)((r2 - lop) * Wn + col) * 8) = ap;
                if (act && i >= 4) {
                    const uintx4 u5 = *(const uintx4*)&m5;
                    const uintx4 u3 = *(const uintx4*)&m3;
                    uintx4 st;
                    #pragma unroll
                    for (int w = 0; w < 4; ++w)
                        st[w] = pack_rne(bf_lo(u5[w]) + bf_lo(u3[w]), bf_hi(u5[w]) + bf_hi(u3[w]));
                    *(uintx4*)(cmx + (size_t)((r3 - lop) * Wn + col) * 8) = st;
                }
                cur = nxt; nxt = nx2;
            }
        }
        __syncthreads();                 // catl ready

        // ---- conv2 on nr rows (nr*56 px) ----
        const int npxc = nr * Wn;                 // 224 or 168
        const int nPT = (npxc + 15) >> 4;         // 14 or 11 px-tiles
        for (int k = 0; k < 7; ++k) {
            const int pt = e + 2 * k;             // interleaved for pass-1 balance
            if (pt >= nPT) break;
            const int px = pt * 16 + m16;
            floatx4 acc = (floatx4){0.f, 0.f, 0.f, 0.f};
            #pragma unroll
            for (int cp = 0; cp < 4; ++cp) {
                // slab = 4*cp + q: quads at bank offsets {0,8,16,24} -> 2-way
                short8 bfr = *(const short8*)(catl + (size_t)(4 * cp + q) * SLAB + (size_t)px * 8);
                acc = __builtin_amdgcn_mfma_f32_16x16x32_bf16(afr[cp], bfr, acc, 0, 0, 0);
            }
            if (px < npxc) {
                #pragma unroll
                for (int r = 0; r < 4; ++r) {
                    float v = fmaf(acc[r], sc2[r], sh2[r]);
                    ob[(size_t)r * HWn + lop * Wn + px] = v > 0.f ? v : 0.f;
                }
            }
        }
        __syncthreads();                 // catl consumed before next pass pool
    }
}

extern "C" void kernel_launch(void* const* d_in, const int* in_sizes, int n_in,
                              void* d_out, int out_size, void* d_ws, size_t ws_size,
                              hipStream_t stream)
{
    const float* x   = (const float*)d_in[0];
    const float* w1  = (const float*)d_in[1];
    const float* w2  = (const float*)d_in[2];
    const float* b1g = (const float*)d_in[3];
    const float* b1b = (const float*)d_in[4];
    const float* b1m = (const float*)d_in[5];
    const float* b1v = (const float*)d_in[6];
    const float* b2g = (const float*)d_in[7];
    const float* b2b = (const float*)d_in[8];
    const float* b2m = (const float*)d_in[9];
    const float* b2v = (const float*)d_in[10];

    float* out = (float*)d_out;
    unsigned short* node0 = (unsigned short*)d_ws;            // 25.7 MB

    k1_conv1<<<dim3(784), dim3(256), 0, stream>>>(x, w1, b1g, b1b, b1m, b1v, node0);
    k23_fused<<<dim3(Bn * NBAND), dim3(512), 0, stream>>>(node0, w2, b2g, b2b, b2m, b2v, out);
}

// Round 10
// 152.365 us; speedup vs baseline: 1.6936x; 1.0681x over previous
//
#include <hip/hip_runtime.h>
#include <cstddef>

#define EPS 1e-5f
static constexpr int Bn = 64, Cn = 64, Hn = 56, Wn = 56, HWn = Hn * Wn; // 3136
static constexpr int RB = 14;         // output rows per band in k23
static constexpr int NBAND = 4;       // 56/14 -> 256 blocks = exactly 1 round of 256 CUs
static constexpr int PR = 5;          // max rows per pass (passes: 5,5,4)
static constexpr int SLAB5 = 2256;    // 5*56*8+16 ushorts; 1128 dw % 32 == 8 -> quad bank offs {0,8,16,24}

typedef __attribute__((ext_vector_type(8))) short short8;
typedef __attribute__((ext_vector_type(4))) unsigned short ushort4v;
typedef __attribute__((ext_vector_type(4))) float floatx4;
typedef __attribute__((ext_vector_type(16))) float floatx16;
typedef __attribute__((ext_vector_type(4))) unsigned int uintx4;
typedef __attribute__((ext_vector_type(2))) unsigned int uintx2;

__device__ __forceinline__ unsigned pack_rne(float a, float b) {
    unsigned ua = __float_as_uint(a), ub = __float_as_uint(b);
    ua = ua + 0x7fffu + ((ua >> 16) & 1u);
    ub = ub + 0x7fffu + ((ub >> 16) & 1u);
    return __builtin_amdgcn_perm(ub, ua, 0x07060302);
}
__device__ __forceinline__ unsigned pack_trunc(float a, float b) {
    return __builtin_amdgcn_perm(__float_as_uint(b), __float_as_uint(a), 0x07060302);
}
__device__ __forceinline__ uintx2 pmax2(uintx2 a, uintx2 b) {
    ushort4v r = __builtin_elementwise_max(*(ushort4v*)&a, *(ushort4v*)&b);
    return *(uintx2*)&r;
}
__device__ __forceinline__ float bf_lo(unsigned u) { return __uint_as_float(u << 16); }
__device__ __forceinline__ float bf_hi(unsigned u) { return __uint_as_float(u & 0xffff0000u); }

// Layouts (bf16):
//   node0: [b][chunk=8][px=3136][j=8]
//   cat (LDS, per <=5-row pass): 16 slabs of SLAB5 ushorts; slab = chunk*2+plane
//     (0 avg, 1 maxsum), element [px_local<=280][j=8]; two ping-pong buffers.

// ---------------------------------------------------------------------------
// K1: verbatim round-9 (passed): 32x32x16 MFMA, direct global B loads issued
// up front, XCD swizzle matching k23's image ownership (node0 stays in L2).
// ---------------------------------------------------------------------------
__global__ __launch_bounds__(256, 3) void k1_conv1(
    const float* __restrict__ x, const float* __restrict__ w1,
    const float* __restrict__ bg, const float* __restrict__ bb,
    const float* __restrict__ bm, const float* __restrict__ bv,
    unsigned short* __restrict__ node0)
{
    __shared__ float scs[64], shs[64];
    const int tid = threadIdx.x;
    if (tid < 64) {
        float sc = bg[tid] * rsqrtf(bv[tid] + EPS);
        scs[tid] = sc;
        shs[tid] = bb[tid] - bm[tid] * sc;
    }
    __syncthreads();
    const int lane = tid & 63;
    const int wv   = tid >> 6;
    const int n    = lane & 31;
    const int h    = lane >> 5;

    short8 afr0[4], afr1[4];
    {
        const float s0 = scs[n], s1 = scs[32 + n];
        #pragma unroll
        for (int kt = 0; kt < 4; ++kt) {
            const float* wp0 = w1 + (size_t)n * 64 + kt * 16 + h * 8;
            floatx4 f0 = *(const floatx4*)wp0;
            floatx4 f1 = *(const floatx4*)(wp0 + 4);
            uintx4 u;
            u.x = pack_rne(f0[0] * s0, f0[1] * s0);
            u.y = pack_rne(f0[2] * s0, f0[3] * s0);
            u.z = pack_rne(f1[0] * s0, f1[1] * s0);
            u.w = pack_rne(f1[2] * s0, f1[3] * s0);
            afr0[kt] = *(short8*)&u;
            const float* wp1 = wp0 + 32 * 64;
            floatx4 g0 = *(const floatx4*)wp1;
            floatx4 g1 = *(const floatx4*)(wp1 + 4);
            uintx4 v;
            v.x = pack_rne(g0[0] * s1, g0[1] * s1);
            v.y = pack_rne(g0[2] * s1, g0[3] * s1);
            v.z = pack_rne(g1[0] * s1, g1[1] * s1);
            v.w = pack_rne(g1[2] * s1, g1[3] * s1);
            afr1[kt] = *(short8*)&v;
        }
    }

    const int bid = blockIdx.x;
    const int xcd = bid & 7;
    const int idx = bid >> 3;                     // 0..97
    const int P = (xcd * 98 + idx) * 256 + wv * 64;
    const int b = P / HWn, p0 = P - b * HWn;      // 64 | 3136: no image crossing
    const float* xb = x + (size_t)b * 64 * HWn + p0 + n;

    float f0[4][8], f1[4][8];
    #pragma unroll
    for (int kt = 0; kt < 4; ++kt)
        #pragma unroll
        for (int j = 0; j < 8; ++j) {
            const float* xp = xb + (size_t)(kt * 16 + h * 8 + j) * HWn;
            f0[kt][j] = xp[0];
            f1[kt][j] = xp[32];
        }

    #pragma unroll
    for (int s = 0; s < 2; ++s) {
        floatx16 acc0, acc1;
        #pragma unroll
        for (int i = 0; i < 16; ++i) { acc0[i] = 0.f; acc1[i] = 0.f; }

        #pragma unroll
        for (int kt = 0; kt < 4; ++kt) {
            float* fr = s ? f1[kt] : f0[kt];
            uintx4 u;
            u.x = pack_trunc(fr[0], fr[1]);
            u.y = pack_trunc(fr[2], fr[3]);
            u.z = pack_trunc(fr[4], fr[5]);
            u.w = pack_trunc(fr[6], fr[7]);
            short8 bfr = *(short8*)&u;
            acc0 = __builtin_amdgcn_mfma_f32_32x32x16_bf16(afr0[kt], bfr, acc0, 0, 0, 0);
            acc1 = __builtin_amdgcn_mfma_f32_32x32x16_bf16(afr1[kt], bfr, acc1, 0, 0, 0);
        }

        #pragma unroll
        for (int oct = 0; oct < 2; ++oct) {
            #pragma unroll
            for (int g = 0; g < 4; ++g) {
                floatx4 sh4 = *(const floatx4*)&shs[oct * 32 + g * 8 + h * 4];
                float v0 = (oct ? acc1[g * 4 + 0] : acc0[g * 4 + 0]) + sh4[0]; v0 = v0 > 0.f ? v0 : 0.f;
                float v1 = (oct ? acc1[g * 4 + 1] : acc0[g * 4 + 1]) + sh4[1]; v1 = v1 > 0.f ? v1 : 0.f;
                float v2 = (oct ? acc1[g * 4 + 2] : acc0[g * 4 + 2]) + sh4[2]; v2 = v2 > 0.f ? v2 : 0.f;
                float v3 = (oct ? acc1[g * 4 + 3] : acc0[g * 4 + 3]) + sh4[3]; v3 = v3 > 0.f ? v3 : 0.f;
                uintx2 st;
                st.x = pack_rne(v0, v1);
                st.y = pack_rne(v2, v3);
                const int chunk = oct * 4 + g;
                *(uintx2*)(node0 + ((size_t)(b * 8 + chunk) * HWn + p0 + s * 32 + n) * 8 + h * 4) = st;
            }
        }
    }
}

// ---------------------------------------------------------------------------
// K23: fused pools + conv2. Block = (b, 14-row band), 1024 thr = 16 waves.
// Grid 256 = exactly one dispatch round (no residency tail).
// Three passes (5,5,4 rows) over ping-pong 5-row cat buffers (144.5 KB LDS).
// Between barriers each wave runs {pool p+1} and {conv2 p}; wv&1 picks the
// order so the CU always mixes pool-bound and MFMA-bound waves (overlap).
// Pool = round-3's verified 16-wave uintx2 window (chunk=wv>>1, col-half);
// conv2 = verified k-slot mapping; masked partial tiles (pad absorbs reads).
// launch_bounds(1024,1): VGPR cap 128 (empirical model 2048/(16*1)); pool
// state (~60) and conv state (~40) are sequentially live -> fits, no spill.
// ---------------------------------------------------------------------------
__global__ __launch_bounds__(1024, 1) void k23_fused(
    const unsigned short* __restrict__ node0,
    const float* __restrict__ w2,
    const float* __restrict__ bg, const float* __restrict__ bb,
    const float* __restrict__ bm, const float* __restrict__ bv,
    float* __restrict__ out)
{
    __shared__ __align__(16) unsigned short catl[2 * 16 * SLAB5 + 64]; // 144.6 KB
    const int tid = threadIdx.x;
    const int lane = tid & 63;
    const int wv = tid >> 6;            // 0..15

    // XCD swizzle (256 = 8*32): XCD x owns images 8x..8x+7 (matches k1).
    const int bid = blockIdx.x;
    const int xcd = bid & 7;
    const int jj = bid >> 3;            // 0..31
    const int b = xcd * 8 + (jj >> 2);
    const int band = jj & 3;
    const int lo = band * RB;

    // pool lane geometry (round-3 verified): wave = (chunk, col-half)
    const int chunk = wv >> 1;
    const int c0 = (wv & 1) * 28;
    const int local = lane >> 1;        // 0..31; stored cols = locals 2..29
    const int col = c0 - 2 + local;
    const int jh = lane & 1;            // 4-channel half
    const bool stcol = (local >= 2) & (local <= 29);
    const unsigned short* nbase = node0 + ((size_t)(b * 8 + chunk) * HWn) * 8 + jh * 4;

    // ---- w2 frags (k-slot layout) + bn2 constants (verified mapping) ----
    const int m16 = lane & 15;
    const int q = lane >> 4;
    const int t = wv & 3;               // oc-tile
    const int e = wv >> 2;              // px-tile offset (0..3)
    short8 afr[4];
    #pragma unroll
    for (int cp = 0; cp < 4; ++cp) {
        const int c = 2 * cp + (q >> 1);
        const int chb = ((q & 1) ? 64 : 0) + 8 * c;
        const float* wp = w2 + (size_t)(t * 16 + m16) * 128 + chb;
        floatx4 f0 = *(const floatx4*)wp;
        floatx4 f1 = *(const floatx4*)(wp + 4);
        uintx4 u;
        u.x = pack_rne(f0[0], f0[1]);
        u.y = pack_rne(f0[2], f0[3]);
        u.z = pack_rne(f1[0], f1[1]);
        u.w = pack_rne(f1[2], f1[3]);
        afr[cp] = *(short8*)&u;
    }
    const int oc0 = t * 16 + q * 4;
    floatx4 g4 = *(const floatx4*)(bg + oc0);
    floatx4 bb4 = *(const floatx4*)(bb + oc0);
    floatx4 mm4 = *(const floatx4*)(bm + oc0);
    floatx4 vv4 = *(const floatx4*)(bv + oc0);
    float sc2[4], sh2[4];
    #pragma unroll
    for (int r = 0; r < 4; ++r) {
        sc2[r] = g4[r] * rsqrtf(vv4[r] + EPS);
        sh2[r] = bb4[r] - mm4[r] * sc2[r];
    }
    float* ob = out + (size_t)(b * 64 + oc0) * HWn;

    const uintx2 zz = (uintx2){0u, 0u};

    // pool pass: rows lop..lop+nr-1 into cbuf (round-3 verified window code)
    auto pool_pass = [&](int lop, int nr, unsigned short* cbuf) {
        unsigned short* cav = cbuf + (size_t)(chunk * 2) * SLAB5 + jh * 4;
        unsigned short* cmx = cav + SLAB5;
        auto loadrow = [&](int r) -> uintx2 {
            if (((unsigned)col >= (unsigned)Wn) | ((unsigned)r >= (unsigned)Hn)) return zz;
            return *(const uintx2*)(nbase + (size_t)(r * Wn + col) * 8);
        };
        float hs1[4], hs2[4];
        #pragma unroll
        for (int c = 0; c < 4; ++c) hs1[c] = hs2[c] = 0.f;
        uintx2 h5a = zz, h5b = zz, h5c = zz, h5d = zz, nh1 = zz, nh2 = zz;

        uintx2 cur = loadrow(lop - 2);
        uintx2 nxt = loadrow(lop - 1);

        for (int i = 0; i < nr + 4; ++i) {
            const int r = lop - 2 + i;
            uintx2 nx2 = (i < nr + 2) ? loadrow(r + 2) : zz;   // 2-deep prefetch

            // column taps via even-delta shuffles (jh parity preserved)
            uintx2 D0, D1, D3, D4;
            #pragma unroll
            for (int w = 0; w < 2; ++w) {
                unsigned u = cur[w];
                D1[w] = __shfl_up(u, 2);
                D0[w] = __shfl_up(u, 4);
                D3[w] = __shfl_down(u, 2);
                D4[w] = __shfl_down(u, 4);
            }

            uintx2 hm5 = pmax2(pmax2(pmax2(D0, D1), pmax2(cur, D3)), D4);
            uintx2 m5 = pmax2(pmax2(pmax2(h5a, h5b), pmax2(h5c, h5d)), hm5);
            h5a = h5b; h5b = h5c; h5c = h5d; h5d = hm5;

            float a2[4];
            #pragma unroll
            for (int w = 0; w < 2; ++w) {
                float s0 = bf_lo(D1[w]) + bf_lo(cur[w]) + bf_lo(D3[w]);
                float s1 = bf_hi(D1[w]) + bf_hi(cur[w]) + bf_hi(D3[w]);
                a2[w * 2 + 0] = (hs2[w * 2 + 0] + hs1[w * 2 + 0] + s0) * (1.f / 9.f);
                a2[w * 2 + 1] = (hs2[w * 2 + 1] + hs1[w * 2 + 1] + s1) * (1.f / 9.f);
                hs2[w * 2 + 0] = hs1[w * 2 + 0]; hs1[w * 2 + 0] = s0;
                hs2[w * 2 + 1] = hs1[w * 2 + 1]; hs1[w * 2 + 1] = s1;
            }
            uintx2 ap;
            ap.x = pack_rne(a2[0], a2[1]);
            ap.y = pack_rne(a2[2], a2[3]);

            uintx2 al, ar;
            #pragma unroll
            for (int w = 0; w < 2; ++w) {
                al[w] = __shfl_up(ap[w], 2);
                ar[w] = __shfl_down(ap[w], 2);
            }
            uintx2 nh = pmax2(pmax2(al, ap), ar);
            uintx2 m3 = pmax2(pmax2(nh2, nh1), nh);
            nh2 = nh1; nh1 = nh;

            const int r2 = r - 1, r3 = r - 2;
            if (stcol && i >= 3 && i <= nr + 2)
                *(uintx2*)(cav + (size_t)((r2 - lop) * Wn + col) * 8) = ap;
            if (stcol && i >= 4) {
                uintx2 st;
                st.x = pack_rne(bf_lo(m5.x) + bf_lo(m3.x), bf_hi(m5.x) + bf_hi(m3.x));
                st.y = pack_rne(bf_lo(m5.y) + bf_lo(m3.y), bf_hi(m5.y) + bf_hi(m3.y));
                *(uintx2*)(cmx + (size_t)((r3 - lop) * Wn + col) * 8) = st;
            }
            cur = nxt; nxt = nx2;
        }
    };

    // conv2 pass: nr rows from cbuf -> out rows lop.. (verified mapping)
    auto conv_pass = [&](int lop, int nr, const unsigned short* cbuf) {
        const int npxc = nr * Wn;                 // 280 or 224
        const int nPT = (npxc + 15) >> 4;         // 18 or 14 px-tiles
        for (int k = 0; k < 5; ++k) {
            const int pt = e + 4 * k;
            if (pt >= nPT) break;
            const int px = pt * 16 + m16;
            floatx4 acc = (floatx4){0.f, 0.f, 0.f, 0.f};
            #pragma unroll
            for (int cp = 0; cp < 4; ++cp) {
                // slab = 4*cp + q: quads at bank offsets {0,8,16,24} -> 2-way
                short8 bfr = *(const short8*)(cbuf + (size_t)(4 * cp + q) * SLAB5 + (size_t)px * 8);
                acc = __builtin_amdgcn_mfma_f32_16x16x32_bf16(afr[cp], bfr, acc, 0, 0, 0);
            }
            if (px < npxc) {
                #pragma unroll
                for (int r = 0; r < 4; ++r) {
                    float v = fmaf(acc[r], sc2[r], sh2[r]);
                    ob[(size_t)r * HWn + lop * Wn + px] = v > 0.f ? v : 0.f;
                }
            }
        }
    };

    unsigned short* buf0 = catl;
    unsigned short* buf1 = catl + 16 * SLAB5;

    // pass 0 pool
    pool_pass(lo, 5, buf0);
    __syncthreads();
    // [pool pass 1 || conv pass 0] -- wave-staggered order for pipe mixing
    if (wv & 1) { pool_pass(lo + 5, 5, buf1); conv_pass(lo, 5, buf0); }
    else        { conv_pass(lo, 5, buf0); pool_pass(lo + 5, 5, buf1); }
    __syncthreads();
    // [pool pass 2 || conv pass 1]
    if (wv & 1) { pool_pass(lo + 10, 4, buf0); conv_pass(lo + 5, 5, buf1); }
    else        { conv_pass(lo + 5, 5, buf1); pool_pass(lo + 10, 4, buf0); }
    __syncthreads();
    // conv pass 2
    conv_pass(lo + 10, 4, buf0);
}

extern "C" void kernel_launch(void* const* d_in, const int* in_sizes, int n_in,
                              void* d_out, int out_size, void* d_ws, size_t ws_size,
                              hipStream_t stream)
{
    const float* x   = (const float*)d_in[0];
    const float* w1  = (const float*)d_in[1];
    const float* w2  = (const float*)d_in[2];
    const float* b1g = (const float*)d_in[3];
    const float* b1b = (const float*)d_in[4];
    const float* b1m = (const float*)d_in[5];
    const float* b1v = (const float*)d_in[6];
    const float* b2g = (const float*)d_in[7];
    const float* b2b = (const float*)d_in[8];
    const float* b2m = (const float*)d_in[9];
    const float* b2v = (const float*)d_in[10];

    float* out = (float*)d_out;
    unsigned short* node0 = (unsigned short*)d_ws;            // 25.7 MB

    k1_conv1<<<dim3(784), dim3(256), 0, stream>>>(x, w1, b1g, b1b, b1m, b1v, node0);
    k23_fused<<<dim3(Bn * NBAND), dim3(1024), 0, stream>>>(node0, w2, b2g, b2b, b2m, b2v, out);
}